// Round 22
// baseline (170.693 us; speedup 1.0000x reference)
//
#include <hip/hip_runtime.h>

#define DIM    64
#define NEMB   1024
#define HW     4096      // 64*64
#define NPIX   131072    // 32*64*64
#define NOUT   8388608   // 32*64*64*64
#define SPIX   128       // pixels per screen block
#define FPIX   64        // pixels per finish block (19KB LDS -> 8 blk/CU)
#define NTILE  64        // 1024/16 code tiles
#define TPW    16        // tiles per wave (4 waves cover 64)
#define CAP    512       // worklist capacity (observed ~85 entries/64-pix block)
#define MARGIN 2.0f      // >= 5x worst-case screen error

using short8 = __attribute__((ext_vector_type(8))) short;
using f32x4  = __attribute__((ext_vector_type(4))) float;

#define MFMA(A, B, C) __builtin_amdgcn_mfma_f32_16x16x32_bf16((A), (B), (C), 0, 0, 0)

__device__ __forceinline__ unsigned short bf16_rne(float f) {
    unsigned u = __float_as_uint(f);
    return (unsigned short)((u + 0x7fffu + ((u >> 16) & 1u)) >> 16);
}
__device__ __forceinline__ void umin64(unsigned long long* p, unsigned long long v) {
    unsigned long long old = *p;
    while (v < old) {
        unsigned long long a = atomicCAS(p, old, v);
        if (a == old) break;
        old = a;
    }
}

// ---------------------------------------------------------------------------
// prep1: cn[j] = ||e_j||^2 (numpy axis-0 order) + cnfrag scatter + loss zero
// ---------------------------------------------------------------------------
__global__ __launch_bounds__(256) void prep1(const float* __restrict__ embed,
                                             float* __restrict__ cn,
                                             float* __restrict__ cnfrag,
                                             float* __restrict__ loss) {
    const int j = blockIdx.x * 256 + threadIdx.x;
    if (j >= NEMB) return;
    if (j == 0) loss[0] = 0.f;
    float v = embed[j];
    float s = __fmul_rn(v, v);
#pragma unroll
    for (int d = 1; d < DIM; ++d) {
        v = embed[d * NEMB + j];
        s = __fadd_rn(s, __fmul_rn(v, v));
    }
    cn[j] = s;
    const int ct = j >> 4, r = j & 15;
#pragma unroll
    for (int i = 0; i < 16; ++i)
        cnfrag[ct * 256 + ((r >> 2) * 16 + i) * 4 + (r & 3)] = s;
}

// ---------------------------------------------------------------------------
// prep2: split -2*embed into bf16 hi/lo in MFMA A-fragment order (== R9-R20,
// verified by absmax=0) + j-major fp32 copy eT[j][d] (epilogue + rescore rows)
// ---------------------------------------------------------------------------
__global__ __launch_bounds__(256) void prep2(const float* __restrict__ embed,
                                             unsigned short* __restrict__ ehi,
                                             unsigned short* __restrict__ elo,
                                             float* __restrict__ eT) {
    const int gid = blockIdx.x * 256 + threadIdx.x;   // 64*1024 elements
    const int d = gid >> 10;
    const int j = gid & 1023;
    const float v0 = embed[d * NEMB + j];
    eT[(size_t)j * DIM + d] = v0;
    const float es = -2.0f * v0;
    const unsigned short h = bf16_rne(es);
    const float hv = __uint_as_float((unsigned)h << 16);
    const unsigned short lo = bf16_rne(es - hv);
    const int ct = j >> 4, r = j & 15;
    const int kc = d >> 5, g = (d >> 3) & 3, i = d & 7;
    const int idx = ((ct * 2 + kc) * 64 + (g * 16 + r)) * 8 + i;
    ehi[idx] = h;
    elo[idx] = lo;
}

// ---------------------------------------------------------------------------
// Kernel A — screen (unchanged from R14-R20): stage x as bf16, MFMA screen,
// per-pixel enumerate -> u64 candidate-tile MASK to global.
// ---------------------------------------------------------------------------
__global__ __launch_bounds__(256)
__attribute__((amdgpu_waves_per_eu(4, 4)))
void screen_kernel(const float* __restrict__ X,
                   const float* __restrict__ cnfrag,
                   const unsigned short* __restrict__ ehi,
                   const unsigned short* __restrict__ elo,
                   unsigned long long* __restrict__ mask_g) {
    __shared__ unsigned short xbf[DIM][SPIX + 2];    // 16.6 KB
    __shared__ _Float16 tm_lds[NTILE][SPIX];         // 16 KB

    const int tid  = threadIdx.x;
    const int l    = tid & 63;
    const int w    = tid >> 6;
    const int pix0 = blockIdx.x * SPIX;
    const int b    = pix0 >> 12;
    const int p0   = pix0 & 4095;

    const int ct0 = w * TPW;
    f32x4  cnc = *(const f32x4*)(cnfrag + (ct0 * 64 + l) * 4);
    short8 eh0 = *(const short8*)(ehi + ((ct0 * 2 + 0) * 64 + l) * 8);
    short8 eh1 = *(const short8*)(ehi + ((ct0 * 2 + 1) * 64 + l) * 8);
    short8 el0 = *(const short8*)(elo + ((ct0 * 2 + 0) * 64 + l) * 8);
    short8 el1 = *(const short8*)(elo + ((ct0 * 2 + 1) * 64 + l) * 8);

    {
        const int sp = tid & (SPIX - 1);
        const int dh = tid >> 7;
        const float* xb = X + (size_t)b * (DIM * HW) + p0 + sp;
#pragma unroll
        for (int k = 0; k < DIM / 2; ++k) {
            const int d = dh * (DIM / 2) + k;
            xbf[d][sp] = bf16_rne(xb[(size_t)d * HW]);
        }
    }
    __syncthreads();

    const int g  = l >> 4;
    const int lr = l & 15;
    short8 xh[8][2];     // 64 VGPR
#pragma unroll
    for (int s = 0; s < 8; ++s)
#pragma unroll
        for (int kc = 0; kc < 2; ++kc)
#pragma unroll
            for (int i = 0; i < 8; ++i) {
                const int d = kc * 32 + g * 8 + i;
                xh[s][kc][i] = (short)xbf[d][s * 16 + lr];
            }

#pragma unroll 1
    for (int t = 0; t < TPW; ++t) {
        const int ct = ct0 + t;
        f32x4 cnn = cnc;
        short8 eh0n = eh0, eh1n = eh1, el0n = el0, el1n = el1;
        if (t + 1 < TPW) {
            const int c2 = (ct + 1) * 2;
            cnn  = *(const f32x4*)(cnfrag + ((ct + 1) * 64 + l) * 4);
            eh0n = *(const short8*)(ehi + ((c2 + 0) * 64 + l) * 8);
            eh1n = *(const short8*)(ehi + ((c2 + 1) * 64 + l) * 8);
            el0n = *(const short8*)(elo + ((c2 + 0) * 64 + l) * 8);
            el1n = *(const short8*)(elo + ((c2 + 1) * 64 + l) * 8);
        }
#pragma unroll
        for (int s = 0; s < 8; ++s) {
            f32x4 c0 = cnc, c1 = {0.f, 0.f, 0.f, 0.f};
            c0 = MFMA(el0, xh[s][0], c0);
            c1 = MFMA(el1, xh[s][1], c1);
            c0 = MFMA(eh0, xh[s][0], c0);
            c1 = MFMA(eh1, xh[s][1], c1);
            float m = fminf(fminf(c0[0] + c1[0], c0[1] + c1[1]),
                            fminf(c0[2] + c1[2], c0[3] + c1[3]));
            m = fminf(m, __shfl_xor(m, 16, 64));
            m = fminf(m, __shfl_xor(m, 32, 64));
            if (l < 16) tm_lds[ct][s * 16 + l] = (_Float16)m;
        }
        cnc = cnn; eh0 = eh0n; eh1 = eh1n; el0 = el0n; el1 = el1n;
    }
    __syncthreads();

    if (tid < SPIX) {
        float m0 = (float)tm_lds[0][tid], m1 = (float)tm_lds[1][tid];
        float m2 = (float)tm_lds[2][tid], m3 = (float)tm_lds[3][tid];
#pragma unroll
        for (int ct = 4; ct < NTILE; ct += 4) {
            m0 = fminf(m0, (float)tm_lds[ct + 0][tid]);
            m1 = fminf(m1, (float)tm_lds[ct + 1][tid]);
            m2 = fminf(m2, (float)tm_lds[ct + 2][tid]);
            m3 = fminf(m3, (float)tm_lds[ct + 3][tid]);
        }
        const float thr = fminf(fminf(m0, m1), fminf(m2, m3)) + MARGIN;
        unsigned long long mk = 0;
#pragma unroll
        for (int ct = 0; ct < NTILE; ++ct)
            if ((float)tm_lds[ct][tid] <= thr) mk |= 1ull << ct;
        mask_g[pix0 + tid] = mk;
    }
}

// ---------------------------------------------------------------------------
// Kernel B — rescore + output, R21 = R19 + asm-pipelined rescore loads.
//  R20 lesson: the compiler will NOT allocate wide load windows from C++
//  (VGPR pinned at 48 across 3 attempts). Remedy (guide T3/T4, rule #18):
//  inline-asm loads + counted vmcnt. Enabler: read e rows from eT (256B
//  contiguous per lane) -> 16 global_load_dwordx4 off ONE base with
//  offset:0..240, ALL issued up front; vmcnt(12/8/4/0)+sched_barrier gates
//  before each 16-fmaf strip. asm defs are non-remat/non-split -> registers
//  are forced. fmaf order strict d=0..63, same float values as embed ->
//  bitwise-identical distances (absmax 0).
// ---------------------------------------------------------------------------
#define LD16(q, off) \
    asm volatile("global_load_dwordx4 %0, %1, off offset:" #off \
                 : "=v"(q) : "v"(ar))
#define FMA_STRIP(q0_, q1_, q2_, q3_, dbase)                       \
    do {                                                           \
        a = fmaf(xp[(dbase) + 0],  (q0_)[0], a);                   \
        a = fmaf(xp[(dbase) + 1],  (q0_)[1], a);                   \
        a = fmaf(xp[(dbase) + 2],  (q0_)[2], a);                   \
        a = fmaf(xp[(dbase) + 3],  (q0_)[3], a);                   \
        a = fmaf(xp[(dbase) + 4],  (q1_)[0], a);                   \
        a = fmaf(xp[(dbase) + 5],  (q1_)[1], a);                   \
        a = fmaf(xp[(dbase) + 6],  (q1_)[2], a);                   \
        a = fmaf(xp[(dbase) + 7],  (q1_)[3], a);                   \
        a = fmaf(xp[(dbase) + 8],  (q2_)[0], a);                   \
        a = fmaf(xp[(dbase) + 9],  (q2_)[1], a);                   \
        a = fmaf(xp[(dbase) + 10], (q2_)[2], a);                   \
        a = fmaf(xp[(dbase) + 11], (q2_)[3], a);                   \
        a = fmaf(xp[(dbase) + 12], (q3_)[0], a);                   \
        a = fmaf(xp[(dbase) + 13], (q3_)[1], a);                   \
        a = fmaf(xp[(dbase) + 14], (q3_)[2], a);                   \
        a = fmaf(xp[(dbase) + 15], (q3_)[3], a);                   \
    } while (0)

__global__ __launch_bounds__(256)
void finish_kernel(const float* __restrict__ X,
                   const float* __restrict__ embed,
                   const float* __restrict__ cn,
                   const float* __restrict__ eT,
                   const unsigned long long* __restrict__ mask_g,
                   float* __restrict__ OUT,
                   float* __restrict__ loss) {
    __shared__ float xlds[FPIX][DIM + 1];           // 16.6 KB (transposed, pad 65)
    __shared__ float ff_lds[FPIX];                  // 256 B
    __shared__ unsigned long long best[FPIX];       // 512 B
    __shared__ unsigned wl[CAP];                    // 2 KB (aliased as sred later)
    __shared__ int wl_cnt, wl_ovf;

    const int tid  = threadIdx.x;
    const int grp  = tid >> 4;       // 16 groups of 16 lanes
    const int cc   = tid & 15;       // code lane within group
    const int pix0 = blockIdx.x * FPIX;
    const int b    = pix0 >> 12;
    const int p0   = pix0 & 4095;

    // ---- stage: all 256 threads, 4 per pixel (256B-coalesced rows)
    {
        const int sp = tid & (FPIX - 1);
        const int dq = tid >> 6;                    // 0..3 -> 16 d's each
        const float* xb = X + (size_t)b * (DIM * HW) + p0 + sp;
#pragma unroll
        for (int k = 0; k < DIM / 4; ++k) {
            const int d = dq * (DIM / 4) + k;
            xlds[sp][d] = xb[(size_t)d * HW];
        }
        if (tid < FPIX) best[tid] = 0xFFFFFFFFFFFFFFFFull;
        if (tid == 0) { wl_cnt = 0; wl_ovf = 0; }
    }
    __syncthreads();

    // ---- ff per pixel (pairwise-8, bitwise == R0), threads 0..63; then
    //      enumerate this pixel's mask into the worklist
    if (tid < FPIX) {
        float rr[8];
#pragma unroll
        for (int i = 0; i < 8; ++i) {
            const float v = xlds[tid][i];
            rr[i] = __fmul_rn(v, v);
        }
#pragma unroll
        for (int i = 8; i < DIM; i += 8)
#pragma unroll
            for (int q = 0; q < 8; ++q) {
                const float v = xlds[tid][i + q];
                rr[q] = __fadd_rn(rr[q], __fmul_rn(v, v));
            }
        ff_lds[tid] = __fadd_rn(
            __fadd_rn(__fadd_rn(rr[0], rr[1]), __fadd_rn(rr[2], rr[3])),
            __fadd_rn(__fadd_rn(rr[4], rr[5]), __fadd_rn(rr[6], rr[7])));

        unsigned long long mk = mask_g[pix0 + tid];
        int slot = atomicAdd(&wl_cnt, __popcll(mk));
        while (mk) {
            const int ct = (int)__builtin_ctzll(mk);
            mk &= mk - 1;
            if (slot < CAP) wl[slot] = (unsigned)((tid << 6) | ct);
            else wl_ovf = 1;
            ++slot;
        }
    }
    __syncthreads();

    // ---- balanced rescore, asm-pipelined: entry -> 16-lane group, lane cc
    //      = code. Lane reads its eT row (256B) via 16 dwordx4 all in
    //      flight; counted vmcnt gates each strip.
    const int ec = wl_cnt < CAP ? wl_cnt : CAP;
#pragma unroll 1
    for (int base = 0; base < ec; base += 16) {
        const int e = base + grp;
        unsigned long long pk = 0xFFFFFFFFFFFFFFFFull;
        int pix = 0;
        if (e < ec) {
            const unsigned ent = wl[e];
            pix = (int)(ent >> 6);
            const int j = (int)(ent & 63) * 16 + cc;
            const float* ar = eT + (size_t)j * DIM;   // lane's contiguous row
            const float* xp = xlds[pix];              // group-uniform broadcast
            f32x4 q0, q1, q2, q3, q4, q5, q6, q7,
                  q8, q9, q10, q11, q12, q13, q14, q15;
            LD16(q0, 0);    LD16(q1, 16);   LD16(q2, 32);   LD16(q3, 48);
            LD16(q4, 64);   LD16(q5, 80);   LD16(q6, 96);   LD16(q7, 112);
            LD16(q8, 128);  LD16(q9, 144);  LD16(q10, 160); LD16(q11, 176);
            LD16(q12, 192); LD16(q13, 208); LD16(q14, 224); LD16(q15, 240);
            float a = 0.f;
            asm volatile("s_waitcnt vmcnt(12)" ::: "memory");
            __builtin_amdgcn_sched_barrier(0);
            FMA_STRIP(q0, q1, q2, q3, 0);             // d 0..15, seq == R0
            asm volatile("s_waitcnt vmcnt(8)" ::: "memory");
            __builtin_amdgcn_sched_barrier(0);
            FMA_STRIP(q4, q5, q6, q7, 16);            // d 16..31
            asm volatile("s_waitcnt vmcnt(4)" ::: "memory");
            __builtin_amdgcn_sched_barrier(0);
            FMA_STRIP(q8, q9, q10, q11, 32);          // d 32..47
            asm volatile("s_waitcnt vmcnt(0)" ::: "memory");
            __builtin_amdgcn_sched_barrier(0);
            FMA_STRIP(q12, q13, q14, q15, 48);        // d 48..63
            const float dist =
                __fadd_rn(__fsub_rn(ff_lds[pix], __fmul_rn(2.f, a)), cn[j]);
            pk = ((unsigned long long)__float_as_uint(dist) << 32) | (unsigned)j;
        }
#pragma unroll
        for (int m = 1; m < 16; m <<= 1) {
            const unsigned long long o = __shfl_xor(pk, m, 64);
            pk = o < pk ? o : pk;
        }
        if (e < ec && cc == 0) umin64(&best[pix], pk);
    }
    __syncthreads();

    if (wl_ovf) {   // safety net (never in practice): mask-walk per pixel
#pragma unroll 1
        for (int t = 0; t < FPIX / 16; ++t) {
            const int pix = t * 16 + grp;
            const float ffv = ff_lds[pix];
            unsigned long long mk = mask_g[pix0 + pix];
            unsigned long long bb = 0xFFFFFFFFFFFFFFFFull;
            while (mk) {
                const int ct = (int)__builtin_ctzll(mk);
                mk &= mk - 1;
                const int j = ct * 16 + cc;
                float a = 0.f;
#pragma unroll
                for (int d = 0; d < DIM; ++d)
                    a = fmaf(xlds[pix][d], embed[(size_t)d * NEMB + j], a);
                const float dist =
                    __fadd_rn(__fsub_rn(ffv, __fmul_rn(2.f, a)), cn[j]);
                const unsigned long long pk2b =
                    ((unsigned long long)__float_as_uint(dist) << 32) | (unsigned)j;
                bb = pk2b < bb ? pk2b : bb;
            }
#pragma unroll
            for (int m = 1; m < 16; m <<= 1) {
                const unsigned long long o = __shfl_xor(bb, m, 64);
                bb = o < bb ? o : bb;
            }
            if (cc == 0) umin64(&best[pix], bb);
        }
        __syncthreads();
    }

    // ---- output + loss: 4 threads per pixel; q from eT rows (R19 layout)
    float* sred = (float*)wl;     // disjoint lifetime
    const int pixe = tid >> 2;
    const int part = tid & 3;
    const int idx  = (int)(best[pixe] & 0xFFFFFFFFull);
    const float* er = eT + (size_t)idx * DIM;
    float lerr = 0.f;
    float* outb = OUT + (size_t)b * (DIM * HW) + p0 + pixe;
#pragma unroll
    for (int k16 = 0; k16 < 4; ++k16) {
        const float4 q4 = *(const float4*)(er + k16 * 16 + part * 4);
#pragma unroll
        for (int e2i = 0; e2i < 4; ++e2i) {
            const int d = k16 * 16 + part * 4 + e2i;
            const float qv = (e2i == 0) ? q4.x : (e2i == 1) ? q4.y
                                       : (e2i == 2) ? q4.z : q4.w;
            const float xv = xlds[pixe][d];
            const float df = __fsub_rn(qv, xv);
            outb[(size_t)d * HW] = __fadd_rn(xv, df);
            lerr = fmaf(df, df, lerr);
        }
    }

    sred[tid] = lerr;
    __syncthreads();
#pragma unroll
    for (int s = 128; s > 0; s >>= 1) {
        if (tid < s) sred[tid] += sred[tid + s];
        __syncthreads();
    }
    if (tid == 0)
        atomicAdd(loss, sred[0] * (1.0f / (float)NOUT));
}

extern "C" void kernel_launch(void* const* d_in, const int* in_sizes, int n_in,
                              void* d_out, int out_size, void* d_ws, size_t ws_size,
                              hipStream_t stream) {
    const float* X = (const float*)d_in[0];
    const float* E = (const float*)d_in[1];
    float* OUT  = (float*)d_out;
    float* loss = OUT + NOUT;

    // ws layout (bytes): cn 4K | cnfrag 64K | ehi 128K | elo 128K | eT 256K | mask 1M
    char* wsb = (char*)d_ws;
    float* cn                 = (float*)(wsb);
    float* cnfrag             = (float*)(wsb + 4096);
    unsigned short* ehi       = (unsigned short*)(wsb + 4096 + 65536);
    unsigned short* elo       = (unsigned short*)(wsb + 4096 + 65536 + 131072);
    float* eT                 = (float*)(wsb + 4096 + 65536 + 262144);
    unsigned long long* maskg = (unsigned long long*)(wsb + 4096 + 65536 + 262144 + 262144);

    prep1<<<NEMB / 256, 256, 0, stream>>>(E, cn, cnfrag, loss);
    prep2<<<(DIM * NEMB) / 256, 256, 0, stream>>>(E, ehi, elo, eT);
    screen_kernel<<<NPIX / SPIX, 256, 0, stream>>>(X, cnfrag, ehi, elo, maskg);
    finish_kernel<<<NPIX / FPIX, 256, 0, stream>>>(X, E, cn, eT, maskg, OUT, loss);
}

// Round 23
// 113.100 us; speedup vs baseline: 1.5092x; 1.5092x over previous
//
#include <hip/hip_runtime.h>

#define DIM    64
#define NEMB   1024
#define HW     4096      // 64*64
#define NPIX   131072    // 32*64*64
#define NOUT   8388608   // 32*64*64*64
#define SPIX   128       // pixels per screen block
#define FPIX   64        // pixels per finish block (19KB LDS -> 8 blk/CU)
#define NTILE  64        // 1024/16 code tiles
#define TPW    16        // tiles per wave (4 waves cover 64)
#define CAP    512       // worklist capacity (observed ~85 entries/64-pix block)
#define MARGIN 2.0f      // >= 5x worst-case screen error

using short8 = __attribute__((ext_vector_type(8))) short;
using f32x4  = __attribute__((ext_vector_type(4))) float;

#define MFMA(A, B, C) __builtin_amdgcn_mfma_f32_16x16x32_bf16((A), (B), (C), 0, 0, 0)

__device__ __forceinline__ unsigned short bf16_rne(float f) {
    unsigned u = __float_as_uint(f);
    return (unsigned short)((u + 0x7fffu + ((u >> 16) & 1u)) >> 16);
}
__device__ __forceinline__ void umin64(unsigned long long* p, unsigned long long v) {
    unsigned long long old = *p;
    while (v < old) {
        unsigned long long a = atomicCAS(p, old, v);
        if (a == old) break;
        old = a;
    }
}

// ---------------------------------------------------------------------------
// prep (merged prep1+prep2): every gid handles one (d,j) element of the
// bf16 hi/lo fragment split + eT scatter; gids < NEMB additionally compute
// cn[j] (numpy axis-0 order), the cnfrag scatter, and zero the loss.
// All arithmetic identical to the R19-verified kernels (absmax 0).
// ---------------------------------------------------------------------------
__global__ __launch_bounds__(256) void prep(const float* __restrict__ embed,
                                            float* __restrict__ cn,
                                            float* __restrict__ cnfrag,
                                            unsigned short* __restrict__ ehi,
                                            unsigned short* __restrict__ elo,
                                            float* __restrict__ eT,
                                            float* __restrict__ loss) {
    const int gid = blockIdx.x * 256 + threadIdx.x;   // 64*1024 elements
    const int d = gid >> 10;
    const int j = gid & 1023;
    const float v0 = embed[d * NEMB + j];
    eT[(size_t)j * DIM + d] = v0;
    const float es = -2.0f * v0;
    const unsigned short h = bf16_rne(es);
    const float hv = __uint_as_float((unsigned)h << 16);
    const unsigned short lo = bf16_rne(es - hv);
    {
        const int ct = j >> 4, r = j & 15;
        const int kc = d >> 5, g = (d >> 3) & 3, i = d & 7;
        const int idx = ((ct * 2 + kc) * 64 + (g * 16 + r)) * 8 + i;
        ehi[idx] = h;
        elo[idx] = lo;
    }
    if (gid < NEMB) {
        if (gid == 0) loss[0] = 0.f;
        float v = embed[gid];
        float s = __fmul_rn(v, v);
#pragma unroll
        for (int dd = 1; dd < DIM; ++dd) {
            v = embed[dd * NEMB + gid];
            s = __fadd_rn(s, __fmul_rn(v, v));
        }
        cn[gid] = s;
        const int ct = gid >> 4, r = gid & 15;
#pragma unroll
        for (int i = 0; i < 16; ++i)
            cnfrag[ct * 256 + ((r >> 2) * 16 + i) * 4 + (r & 3)] = s;
    }
}

// ---------------------------------------------------------------------------
// Kernel A — screen (unchanged from R14-R19): stage x as bf16, MFMA screen,
// per-pixel enumerate -> u64 candidate-tile MASK to global.
// ---------------------------------------------------------------------------
__global__ __launch_bounds__(256)
__attribute__((amdgpu_waves_per_eu(4, 4)))
void screen_kernel(const float* __restrict__ X,
                   const float* __restrict__ cnfrag,
                   const unsigned short* __restrict__ ehi,
                   const unsigned short* __restrict__ elo,
                   unsigned long long* __restrict__ mask_g) {
    __shared__ unsigned short xbf[DIM][SPIX + 2];    // 16.6 KB
    __shared__ _Float16 tm_lds[NTILE][SPIX];         // 16 KB

    const int tid  = threadIdx.x;
    const int l    = tid & 63;
    const int w    = tid >> 6;
    const int pix0 = blockIdx.x * SPIX;
    const int b    = pix0 >> 12;
    const int p0   = pix0 & 4095;

    const int ct0 = w * TPW;
    f32x4  cnc = *(const f32x4*)(cnfrag + (ct0 * 64 + l) * 4);
    short8 eh0 = *(const short8*)(ehi + ((ct0 * 2 + 0) * 64 + l) * 8);
    short8 eh1 = *(const short8*)(ehi + ((ct0 * 2 + 1) * 64 + l) * 8);
    short8 el0 = *(const short8*)(elo + ((ct0 * 2 + 0) * 64 + l) * 8);
    short8 el1 = *(const short8*)(elo + ((ct0 * 2 + 1) * 64 + l) * 8);

    {
        const int sp = tid & (SPIX - 1);
        const int dh = tid >> 7;
        const float* xb = X + (size_t)b * (DIM * HW) + p0 + sp;
#pragma unroll
        for (int k = 0; k < DIM / 2; ++k) {
            const int d = dh * (DIM / 2) + k;
            xbf[d][sp] = bf16_rne(xb[(size_t)d * HW]);
        }
    }
    __syncthreads();

    const int g  = l >> 4;
    const int lr = l & 15;
    short8 xh[8][2];     // 64 VGPR
#pragma unroll
    for (int s = 0; s < 8; ++s)
#pragma unroll
        for (int kc = 0; kc < 2; ++kc)
#pragma unroll
            for (int i = 0; i < 8; ++i) {
                const int d = kc * 32 + g * 8 + i;
                xh[s][kc][i] = (short)xbf[d][s * 16 + lr];
            }

#pragma unroll 1
    for (int t = 0; t < TPW; ++t) {
        const int ct = ct0 + t;
        f32x4 cnn = cnc;
        short8 eh0n = eh0, eh1n = eh1, el0n = el0, el1n = el1;
        if (t + 1 < TPW) {
            const int c2 = (ct + 1) * 2;
            cnn  = *(const f32x4*)(cnfrag + ((ct + 1) * 64 + l) * 4);
            eh0n = *(const short8*)(ehi + ((c2 + 0) * 64 + l) * 8);
            eh1n = *(const short8*)(ehi + ((c2 + 1) * 64 + l) * 8);
            el0n = *(const short8*)(elo + ((c2 + 0) * 64 + l) * 8);
            el1n = *(const short8*)(elo + ((c2 + 1) * 64 + l) * 8);
        }
#pragma unroll
        for (int s = 0; s < 8; ++s) {
            f32x4 c0 = cnc, c1 = {0.f, 0.f, 0.f, 0.f};
            c0 = MFMA(el0, xh[s][0], c0);
            c1 = MFMA(el1, xh[s][1], c1);
            c0 = MFMA(eh0, xh[s][0], c0);
            c1 = MFMA(eh1, xh[s][1], c1);
            float m = fminf(fminf(c0[0] + c1[0], c0[1] + c1[1]),
                            fminf(c0[2] + c1[2], c0[3] + c1[3]));
            m = fminf(m, __shfl_xor(m, 16, 64));
            m = fminf(m, __shfl_xor(m, 32, 64));
            if (l < 16) tm_lds[ct][s * 16 + l] = (_Float16)m;
        }
        cnc = cnn; eh0 = eh0n; eh1 = eh1n; el0 = el0n; el1 = el1n;
    }
    __syncthreads();

    if (tid < SPIX) {
        float m0 = (float)tm_lds[0][tid], m1 = (float)tm_lds[1][tid];
        float m2 = (float)tm_lds[2][tid], m3 = (float)tm_lds[3][tid];
#pragma unroll
        for (int ct = 4; ct < NTILE; ct += 4) {
            m0 = fminf(m0, (float)tm_lds[ct + 0][tid]);
            m1 = fminf(m1, (float)tm_lds[ct + 1][tid]);
            m2 = fminf(m2, (float)tm_lds[ct + 2][tid]);
            m3 = fminf(m3, (float)tm_lds[ct + 3][tid]);
        }
        const float thr = fminf(fminf(m0, m1), fminf(m2, m3)) + MARGIN;
        unsigned long long mk = 0;
#pragma unroll
        for (int ct = 0; ct < NTILE; ++ct)
            if ((float)tm_lds[ct][tid] <= thr) mk |= 1ull << ct;
        mask_g[pix0 + tid] = mk;
    }
}

// ---------------------------------------------------------------------------
// Kernel B — rescore + output (exact R19 configuration, the proven best:
// column-major coalesced rescore loads, transposed xlds, eT-row epilogue).
// ---------------------------------------------------------------------------
__global__ __launch_bounds__(256)
void finish_kernel(const float* __restrict__ X,
                   const float* __restrict__ embed,
                   const float* __restrict__ cn,
                   const float* __restrict__ eT,
                   const unsigned long long* __restrict__ mask_g,
                   float* __restrict__ OUT,
                   float* __restrict__ loss) {
    __shared__ float xlds[FPIX][DIM + 1];           // 16.6 KB (transposed, pad 65)
    __shared__ float ff_lds[FPIX];                  // 256 B
    __shared__ unsigned long long best[FPIX];       // 512 B
    __shared__ unsigned wl[CAP];                    // 2 KB (aliased as sred later)
    __shared__ int wl_cnt, wl_ovf;

    const int tid  = threadIdx.x;
    const int grp  = tid >> 4;       // 16 groups of 16 lanes
    const int cc   = tid & 15;       // code lane within group
    const int pix0 = blockIdx.x * FPIX;
    const int b    = pix0 >> 12;
    const int p0   = pix0 & 4095;

    // ---- stage: all 256 threads, 4 per pixel (256B-coalesced rows)
    {
        const int sp = tid & (FPIX - 1);
        const int dq = tid >> 6;                    // 0..3 -> 16 d's each
        const float* xb = X + (size_t)b * (DIM * HW) + p0 + sp;
#pragma unroll
        for (int k = 0; k < DIM / 4; ++k) {
            const int d = dq * (DIM / 4) + k;
            xlds[sp][d] = xb[(size_t)d * HW];
        }
        if (tid < FPIX) best[tid] = 0xFFFFFFFFFFFFFFFFull;
        if (tid == 0) { wl_cnt = 0; wl_ovf = 0; }
    }
    __syncthreads();

    // ---- ff per pixel (pairwise-8, bitwise == R0), threads 0..63; then
    //      enumerate this pixel's mask into the worklist
    if (tid < FPIX) {
        float rr[8];
#pragma unroll
        for (int i = 0; i < 8; ++i) {
            const float v = xlds[tid][i];
            rr[i] = __fmul_rn(v, v);
        }
#pragma unroll
        for (int i = 8; i < DIM; i += 8)
#pragma unroll
            for (int q = 0; q < 8; ++q) {
                const float v = xlds[tid][i + q];
                rr[q] = __fadd_rn(rr[q], __fmul_rn(v, v));
            }
        ff_lds[tid] = __fadd_rn(
            __fadd_rn(__fadd_rn(rr[0], rr[1]), __fadd_rn(rr[2], rr[3])),
            __fadd_rn(__fadd_rn(rr[4], rr[5]), __fadd_rn(rr[6], rr[7])));

        unsigned long long mk = mask_g[pix0 + tid];
        int slot = atomicAdd(&wl_cnt, __popcll(mk));
        while (mk) {
            const int ct = (int)__builtin_ctzll(mk);
            mk &= mk - 1;
            if (slot < CAP) wl[slot] = (unsigned)((tid << 6) | ct);
            else wl_ovf = 1;
            ++slot;
        }
    }
    __syncthreads();

    // ---- balanced rescore: entry -> 16-lane group, lane cc = code.
    //      Column-major loads: 16 lanes x 4B consecutive j = one full 64B
    //      line per instruction (optimal). Strip-mined (ping-pong); fmaf
    //      order strict d 0..63 == R0 bitwise.
    const int ec = wl_cnt < CAP ? wl_cnt : CAP;
#pragma unroll 1
    for (int base = 0; base < ec; base += 16) {
        const int e = base + grp;
        unsigned long long pk = 0xFFFFFFFFFFFFFFFFull;
        int pix = 0;
        if (e < ec) {
            const unsigned ent = wl[e];
            pix = (int)(ent >> 6);
            const int j = (int)(ent & 63) * 16 + cc;
            const float* eb = embed + j;
            float evA[16], evB[16];
#pragma unroll
            for (int k = 0; k < 16; ++k) evA[k] = eb[(size_t)k * NEMB];
#pragma unroll
            for (int k = 0; k < 16; ++k) evB[k] = eb[(size_t)(16 + k) * NEMB];
            float a = 0.f;
#pragma unroll
            for (int k = 0; k < 16; ++k) a = fmaf(xlds[pix][k], evA[k], a);
#pragma unroll
            for (int k = 0; k < 16; ++k) evA[k] = eb[(size_t)(32 + k) * NEMB];
#pragma unroll
            for (int k = 0; k < 16; ++k) a = fmaf(xlds[pix][16 + k], evB[k], a);
#pragma unroll
            for (int k = 0; k < 16; ++k) evB[k] = eb[(size_t)(48 + k) * NEMB];
#pragma unroll
            for (int k = 0; k < 16; ++k) a = fmaf(xlds[pix][32 + k], evA[k], a);
#pragma unroll
            for (int k = 0; k < 16; ++k) a = fmaf(xlds[pix][48 + k], evB[k], a);
            const float dist =
                __fadd_rn(__fsub_rn(ff_lds[pix], __fmul_rn(2.f, a)), cn[j]);
            pk = ((unsigned long long)__float_as_uint(dist) << 32) | (unsigned)j;
        }
#pragma unroll
        for (int m = 1; m < 16; m <<= 1) {
            const unsigned long long o = __shfl_xor(pk, m, 64);
            pk = o < pk ? o : pk;
        }
        if (e < ec && cc == 0) umin64(&best[pix], pk);
    }
    __syncthreads();

    if (wl_ovf) {   // safety net (never in practice): mask-walk per pixel
#pragma unroll 1
        for (int t = 0; t < FPIX / 16; ++t) {
            const int pix = t * 16 + grp;
            const float ffv = ff_lds[pix];
            unsigned long long mk = mask_g[pix0 + pix];
            unsigned long long bb = 0xFFFFFFFFFFFFFFFFull;
            while (mk) {
                const int ct = (int)__builtin_ctzll(mk);
                mk &= mk - 1;
                const int j = ct * 16 + cc;
                float a = 0.f;
#pragma unroll
                for (int d = 0; d < DIM; ++d)
                    a = fmaf(xlds[pix][d], embed[(size_t)d * NEMB + j], a);
                const float dist =
                    __fadd_rn(__fsub_rn(ffv, __fmul_rn(2.f, a)), cn[j]);
                const unsigned long long pk2b =
                    ((unsigned long long)__float_as_uint(dist) << 32) | (unsigned)j;
                bb = pk2b < bb ? pk2b : bb;
            }
#pragma unroll
            for (int m = 1; m < 16; m <<= 1) {
                const unsigned long long o = __shfl_xor(bb, m, 64);
                bb = o < bb ? o : bb;
            }
            if (cc == 0) umin64(&best[pix], bb);
        }
        __syncthreads();
    }

    // ---- output + loss: 4 threads per pixel; q from eT rows (R19 layout)
    float* sred = (float*)wl;     // disjoint lifetime
    const int pixe = tid >> 2;
    const int part = tid & 3;
    const int idx  = (int)(best[pixe] & 0xFFFFFFFFull);
    const float* er = eT + (size_t)idx * DIM;
    float lerr = 0.f;
    float* outb = OUT + (size_t)b * (DIM * HW) + p0 + pixe;
#pragma unroll
    for (int k16 = 0; k16 < 4; ++k16) {
        const float4 q4 = *(const float4*)(er + k16 * 16 + part * 4);
#pragma unroll
        for (int e2i = 0; e2i < 4; ++e2i) {
            const int d = k16 * 16 + part * 4 + e2i;
            const float qv = (e2i == 0) ? q4.x : (e2i == 1) ? q4.y
                                       : (e2i == 2) ? q4.z : q4.w;
            const float xv = xlds[pixe][d];
            const float df = __fsub_rn(qv, xv);
            outb[(size_t)d * HW] = __fadd_rn(xv, df);
            lerr = fmaf(df, df, lerr);
        }
    }

    sred[tid] = lerr;
    __syncthreads();
#pragma unroll
    for (int s = 128; s > 0; s >>= 1) {
        if (tid < s) sred[tid] += sred[tid + s];
        __syncthreads();
    }
    if (tid == 0)
        atomicAdd(loss, sred[0] * (1.0f / (float)NOUT));
}

extern "C" void kernel_launch(void* const* d_in, const int* in_sizes, int n_in,
                              void* d_out, int out_size, void* d_ws, size_t ws_size,
                              hipStream_t stream) {
    const float* X = (const float*)d_in[0];
    const float* E = (const float*)d_in[1];
    float* OUT  = (float*)d_out;
    float* loss = OUT + NOUT;

    // ws layout (bytes): cn 4K | cnfrag 64K | ehi 128K | elo 128K | eT 256K | mask 1M
    char* wsb = (char*)d_ws;
    float* cn                 = (float*)(wsb);
    float* cnfrag             = (float*)(wsb + 4096);
    unsigned short* ehi       = (unsigned short*)(wsb + 4096 + 65536);
    unsigned short* elo       = (unsigned short*)(wsb + 4096 + 65536 + 131072);
    float* eT                 = (float*)(wsb + 4096 + 65536 + 262144);
    unsigned long long* maskg = (unsigned long long*)(wsb + 4096 + 65536 + 262144 + 262144);

    prep<<<(DIM * NEMB) / 256, 256, 0, stream>>>(E, cn, cnfrag, ehi, elo, eT, loss);
    screen_kernel<<<NPIX / SPIX, 256, 0, stream>>>(X, cnfrag, ehi, elo, maskg);
    finish_kernel<<<NPIX / FPIX, 256, 0, stream>>>(X, E, cn, eT, maskg, OUT, loss);
}